// Round 2
// baseline (512.739 us; speedup 1.0000x reference)
//
#include <hip/hip_runtime.h>

// ---------------- types & helpers ----------------
typedef __bf16 bf16x8 __attribute__((ext_vector_type(8)));
typedef float f32x4 __attribute__((ext_vector_type(4)));
typedef unsigned short u16x4 __attribute__((ext_vector_type(4)));
typedef unsigned short u16x8 __attribute__((ext_vector_type(8)));

#define DEVI __device__ __forceinline__

DEVI unsigned short f2b(float f) {
  union { float f; unsigned u; } v; v.f = f;
  unsigned r = (v.u + 0x7FFFu + ((v.u >> 16) & 1u)) >> 16;
  return (unsigned short)r;
}
DEVI float b2f(unsigned short h) {
  union { unsigned u; float f; } v; v.u = ((unsigned)h) << 16;
  return v.f;
}
DEVI float silu_f(float v) { return v / (1.f + __expf(-v)); }

DEVI void gload_lds16(const void* g, void* l) {
  __builtin_amdgcn_global_load_lds(
      (const __attribute__((address_space(1))) unsigned int*)g,
      (__attribute__((address_space(3))) unsigned int*)l, 16, 0, 0);
}

#define ALPHA 0.08838834764831845f
#define SILU_SCALE 0.0009765625f
#define LN_EPS 1e-5f

// ---------------- convert fp32 -> bf16 ----------------
__global__ __launch_bounds__(256, 4) void cvt_bf16_kernel(
    const float* __restrict__ src, unsigned short* __restrict__ dst, int n4) {
  int i = blockIdx.x * 256 + threadIdx.x;
  int stride = gridDim.x * 256;
  for (; i < n4; i += stride) {
    f32x4 f = ((const f32x4*)src)[i];
    u16x4 o;
    #pragma unroll
    for (int j = 0; j < 4; ++j) o[j] = f2b(f[j]);
    ((u16x4*)dst)[i] = o;
  }
}

// ---------------- transpose W_proj [1024,1024] f32 -> WpT [1024,1024] bf16 ----------------
__global__ __launch_bounds__(256, 4) void transpose_wp_kernel(
    const float* __restrict__ Wp, unsigned short* __restrict__ WpT) {
  __shared__ unsigned short lT[64 * 68];
  int tid = threadIdx.x;
  int r0 = blockIdx.y * 64, c0 = blockIdx.x * 64;
  #pragma unroll
  for (int p = 0; p < 4; ++p) {
    int r = p * 16 + (tid >> 4);
    int c = (tid & 15) * 4;
    f32x4 f = *(const f32x4*)(Wp + (size_t)(r0 + r) * 1024 + c0 + c);
    #pragma unroll
    for (int i = 0; i < 4; ++i) lT[(c + i) * 68 + r] = f2b(f[i]);
  }
  __syncthreads();
  #pragma unroll
  for (int p = 0; p < 4; ++p) {
    int j = p * 16 + (tid >> 4);
    int i0 = (tid & 15) * 4;
    u16x4 o;
    #pragma unroll
    for (int q = 0; q < 4; ++q) o[q] = lT[j * 68 + i0 + q];
    *(u16x4*)(WpT + (size_t)(c0 + j) * 1024 + r0 + i0) = o;
  }
}

// ---------------- LN1: x f32 [N,1024] -> normed bf16 ----------------
__global__ __launch_bounds__(256, 4) void ln1_kernel(
    const float* __restrict__ x, const float* __restrict__ w,
    const float* __restrict__ bwt, unsigned short* __restrict__ out) {
  __shared__ float red[8];
  int row = blockIdx.x, tid = threadIdx.x;
  f32x4 f = ((const f32x4*)(x + (size_t)row * 1024))[tid];
  float s1 = f[0] + f[1] + f[2] + f[3];
  float s2 = f[0] * f[0] + f[1] * f[1] + f[2] * f[2] + f[3] * f[3];
  #pragma unroll
  for (int off = 32; off > 0; off >>= 1) {
    s1 += __shfl_down(s1, off);
    s2 += __shfl_down(s2, off);
  }
  if ((tid & 63) == 0) { red[(tid >> 6) * 2] = s1; red[(tid >> 6) * 2 + 1] = s2; }
  __syncthreads();
  s1 = red[0] + red[2] + red[4] + red[6];
  s2 = red[1] + red[3] + red[5] + red[7];
  float mu = s1 * (1.f / 1024.f);
  float rstd = rsqrtf(s2 * (1.f / 1024.f) - mu * mu + LN_EPS);
  f32x4 wv = ((const f32x4*)w)[tid];
  f32x4 bv = ((const f32x4*)bwt)[tid];
  u16x4 o;
  #pragma unroll
  for (int i = 0; i < 4; ++i) o[i] = f2b((f[i] - mu) * rstd * wv[i] + bv[i]);
  ((u16x4*)(out + (size_t)row * 1024))[tid] = o;
}

// ---------------- LN2 * u: attn bf16 -> parallel bf16 (into mixed cols 1024..2047) ----------------
__global__ __launch_bounds__(256, 4) void ln2_kernel(
    const unsigned short* __restrict__ attn, unsigned short* __restrict__ mixed,
    const float* __restrict__ w, const float* __restrict__ bwt) {
  __shared__ float red[8];
  int row = blockIdx.x, tid = threadIdx.x;
  u16x4 av = ((const u16x4*)(attn + (size_t)row * 1024))[tid];
  float f0 = b2f(av[0]), f1 = b2f(av[1]), f2v = b2f(av[2]), f3 = b2f(av[3]);
  float s1 = f0 + f1 + f2v + f3;
  float s2 = f0 * f0 + f1 * f1 + f2v * f2v + f3 * f3;
  #pragma unroll
  for (int off = 32; off > 0; off >>= 1) {
    s1 += __shfl_down(s1, off);
    s2 += __shfl_down(s2, off);
  }
  if ((tid & 63) == 0) { red[(tid >> 6) * 2] = s1; red[(tid >> 6) * 2 + 1] = s2; }
  __syncthreads();
  s1 = red[0] + red[2] + red[4] + red[6];
  s2 = red[1] + red[3] + red[5] + red[7];
  float mu = s1 * (1.f / 1024.f);
  float rstd = rsqrtf(s2 * (1.f / 1024.f) - mu * mu + LN_EPS);
  f32x4 wv = ((const f32x4*)w)[tid];
  f32x4 bv = ((const f32x4*)bwt)[tid];
  u16x4 uv = ((const u16x4*)(mixed + (size_t)row * 4096))[tid];
  float n0 = (f0 - mu) * rstd * wv[0] + bv[0];
  float n1 = (f1 - mu) * rstd * wv[1] + bv[1];
  float n2 = (f2v - mu) * rstd * wv[2] + bv[2];
  float n3 = (f3 - mu) * rstd * wv[3] + bv[3];
  u16x4 o;
  o[0] = f2b(b2f(uv[0]) * n0);
  o[1] = f2b(b2f(uv[1]) * n1);
  o[2] = f2b(b2f(uv[2]) * n2);
  o[3] = f2b(b2f(uv[3]) * n3);
  ((u16x4*)(mixed + (size_t)row * 4096 + 1024))[tid] = o;
}

// ---------------- GEMM C = A @ B^T (+epilogue), 128x128 tile, BK=64, swizzled LDS ----------------
// EPI=0: Cb = bf16(silu(acc + aux[col]))   (GEMM1: mixed)
// EPI=1: Cf = acc + aux[row*ldc+col]       (GEMM2: out fp32 + residual x)
template <int EPI>
__global__ __launch_bounds__(256, 2) void gemm_bt_kernel(
    const unsigned short* __restrict__ A, int lda,
    const unsigned short* __restrict__ Bt, int ldb,
    unsigned short* __restrict__ Cb, float* __restrict__ Cf, int ldc,
    const float* __restrict__ aux, int K) {
  __shared__ unsigned short lA[128 * 64];
  __shared__ unsigned short lB[128 * 64];
  const int tid = threadIdx.x, wave = tid >> 6, lane = tid & 63;
  const int row0 = blockIdx.x * 128, col0 = blockIdx.y * 128;
  const int wr = wave >> 1, wc = wave & 1;
  const int sr = tid >> 3;              // 0..31 (row within issue)
  const int kel = ((tid & 7) ^ (sr & 7)) * 8;  // pre-swizzled source k-offset
  f32x4 acc[4][4] = {};
  for (int k0 = 0; k0 < K; k0 += 64) {
    #pragma unroll
    for (int is = 0; is < 4; ++is) {
      int r = is * 32 + sr;
      gload_lds16(A + (size_t)(row0 + r) * lda + k0 + kel, lA + is * 2048 + wave * 512);
      gload_lds16(Bt + (size_t)(col0 + r) * ldb + k0 + kel, lB + is * 2048 + wave * 512);
    }
    __syncthreads();
    #pragma unroll
    for (int kk = 0; kk < 2; ++kk) {
      const int cb = (lane >> 4) * 16 + kk * 64;  // logical col-byte in 128B row
      bf16x8 af[4], bfr[4];
      #pragma unroll
      for (int i = 0; i < 4; ++i) {
        int ra = wr * 64 + i * 16 + (lane & 15);
        af[i] = *(const bf16x8*)(lA + ra * 64 + ((cb ^ ((ra & 7) << 4)) >> 1));
        int rb = wc * 64 + i * 16 + (lane & 15);
        bfr[i] = *(const bf16x8*)(lB + rb * 64 + ((cb ^ ((rb & 7) << 4)) >> 1));
      }
      #pragma unroll
      for (int i = 0; i < 4; ++i)
        #pragma unroll
        for (int j = 0; j < 4; ++j)
          acc[i][j] = __builtin_amdgcn_mfma_f32_16x16x32_bf16(af[i], bfr[j], acc[i][j], 0, 0, 0);
    }
    __syncthreads();
  }
  const int cr = (lane >> 4) * 4, cc = lane & 15;
  #pragma unroll
  for (int i = 0; i < 4; ++i) {
    int grow0 = row0 + wr * 64 + i * 16 + cr;
    #pragma unroll
    for (int j = 0; j < 4; ++j) {
      int gcol = col0 + wc * 64 + j * 16 + cc;
      if (EPI == 0) {
        float bvv = aux[gcol];
        #pragma unroll
        for (int r = 0; r < 4; ++r)
          Cb[(size_t)(grow0 + r) * ldc + gcol] = f2b(silu_f(acc[i][j][r] + bvv));
      } else {
        #pragma unroll
        for (int r = 0; r < 4; ++r) {
          size_t idx = (size_t)(grow0 + r) * ldc + gcol;
          Cf[idx] = acc[i][j][r] + aux[idx];
        }
      }
    }
  }
}

// ---------------- V transpose: mixed v-cols -> vT [B,H,D,S] bf16 ----------------
__global__ __launch_bounds__(256, 4) void vtrans_kernel(
    const unsigned short* __restrict__ mixed, unsigned short* __restrict__ vT) {
  __shared__ unsigned short lT[128 * 64];
  const int tid = threadIdx.x;
  const int s0 = blockIdx.x * 64, h = blockIdx.y, b = blockIdx.z;
  const unsigned short* vp = mixed + (size_t)b * 1024 * 4096 + 1024 + h * 128;
  #pragma unroll
  for (int p = 0; p < 4; ++p) {
    int sl = p * 16 + (tid >> 4);
    int d0 = (tid & 15) * 8;
    u16x8 val = *(const u16x8*)(vp + (size_t)(s0 + sl) * 4096 + d0);
    #pragma unroll
    for (int i = 0; i < 8; ++i) {
      int d = d0 + i;
      lT[d * 64 + ((((sl * 2) ^ ((((d >> 3) & 7)) << 4))) >> 1)] = val[i];
    }
  }
  __syncthreads();
  unsigned short* op = vT + (size_t)(b * 8 + h) * 128 * 1024;
  #pragma unroll
  for (int p = 0; p < 4; ++p) {
    int d = p * 32 + (tid >> 3);
    int sg = (tid & 7) * 8;
    u16x8 o = *(const u16x8*)(lT + d * 64 + ((((sg * 2) ^ ((((d >> 3) & 7)) << 4))) >> 1));
    *(u16x8*)(op + (size_t)d * 1024 + s0 + sg) = o;
  }
}

// ---------------- causal SiLU attention ----------------
// grid (S/64, H, B), 256 thr. Q-tile 64 rows (16/wave); K/V tiles 64.
__global__ __launch_bounds__(256, 2) void attn_kernel(
    const unsigned short* __restrict__ mixed, const unsigned short* __restrict__ vT,
    unsigned short* __restrict__ attnout) {
  __shared__ unsigned short lK[64 * 128];   // [t][d] swizzled rows(256B)
  __shared__ unsigned short lV[128 * 64];   // [d][t] swizzled rows(128B)
  __shared__ unsigned short lW[4 * 16 * 64];  // per-wave [q][t] swizzled rows(128B)
  const int tid = threadIdx.x, wave = tid >> 6, lane = tid & 63;
  const int blkq = blockIdx.x, h = blockIdx.y, b = blockIdx.z;
  const int Q0 = blkq * 64;
  const size_t rowbase = (size_t)b * 1024 * 4096;
  const unsigned short* qp = mixed + rowbase + 2048 + h * 128;
  const unsigned short* kp = mixed + rowbase + 3072 + h * 128;
  const unsigned short* vp = vT + (size_t)(b * 8 + h) * 128 * 1024;
  bf16x8 qf[4];
  {
    int qrow = Q0 + wave * 16 + (lane & 15);
    #pragma unroll
    for (int kk = 0; kk < 4; ++kk)
      qf[kk] = *(const bf16x8*)(qp + (size_t)qrow * 4096 + (lane >> 4) * 8 + kk * 32);
  }
  f32x4 oacc[8] = {};
  unsigned short* lWw = lW + wave * 1024;
  for (int t0 = 0; t0 <= Q0; t0 += 64) {
    {  // stage K tile (4 issues x 16 rows) and V tile (4 issues x 32 rows)
      int rr = tid >> 4, gg = tid & 15;
      #pragma unroll
      for (int is = 0; is < 4; ++is) {
        int row = is * 16 + rr;
        gload_lds16(kp + (size_t)(t0 + row) * 4096 + (size_t)((gg ^ (row & 7)) * 8),
                    lK + is * 2048 + wave * 512);
      }
      int dr = tid >> 3, g2 = tid & 7;
      #pragma unroll
      for (int is = 0; is < 4; ++is) {
        int d = is * 32 + dr;
        gload_lds16(vp + (size_t)d * 1024 + t0 + ((g2 ^ (d & 7)) * 8),
                    lV + is * 2048 + wave * 512);
      }
    }
    __syncthreads();
    f32x4 sacc[4] = {};
    #pragma unroll
    for (int kk = 0; kk < 4; ++kk) {
      #pragma unroll
      for (int f = 0; f < 4; ++f) {
        int trow = f * 16 + (lane & 15);
        int cb = (lane >> 4) * 16 + kk * 64;
        bf16x8 kf = *(const bf16x8*)(lK + trow * 128 + ((cb ^ ((trow & 7) << 4)) >> 1));
        sacc[f] = __builtin_amdgcn_mfma_f32_16x16x32_bf16(qf[kk], kf, sacc[f], 0, 0, 0);
      }
    }
    const bool diag = (t0 == Q0);
    #pragma unroll
    for (int f = 0; f < 4; ++f) {
      int t = f * 16 + (lane & 15);
      #pragma unroll
      for (int r = 0; r < 4; ++r) {
        int q = (lane >> 4) * 4 + r;
        float s = sacc[f][r] * ALPHA;
        float w = silu_f(s) * SILU_SCALE;
        if (diag && t > wave * 16 + q) w = 0.f;
        lWw[q * 64 + (((t * 2) ^ ((q & 7) << 4)) >> 1)] = f2b(w);
      }
    }
    #pragma unroll
    for (int kk = 0; kk < 2; ++kk) {
      int qr = lane & 15;
      int cb = (lane >> 4) * 16 + kk * 64;
      bf16x8 wf = *(const bf16x8*)(lWw + qr * 64 + ((cb ^ ((qr & 7) << 4)) >> 1));
      #pragma unroll
      for (int nf = 0; nf < 8; ++nf) {
        int dr2 = nf * 16 + (lane & 15);
        bf16x8 vf = *(const bf16x8*)(lV + dr2 * 64 + ((cb ^ ((dr2 & 7) << 4)) >> 1));
        oacc[nf] = __builtin_amdgcn_mfma_f32_16x16x32_bf16(wf, vf, oacc[nf], 0, 0, 0);
      }
    }
    __syncthreads();
  }
  const int cr = (lane >> 4) * 4, cc = lane & 15;
  #pragma unroll
  for (int nf = 0; nf < 8; ++nf) {
    int d = nf * 16 + cc;
    #pragma unroll
    for (int r = 0; r < 4; ++r) {
      int q = Q0 + wave * 16 + cr + r;
      attnout[((size_t)b * 1024 + q) * 1024 + h * 128 + d] = f2b(oacc[nf][r]);
    }
  }
}

// ---------------- launcher ----------------
extern "C" void kernel_launch(void* const* d_in, const int* in_sizes, int n_in,
                              void* d_out, int out_size, void* d_ws, size_t ws_size,
                              hipStream_t stream) {
  const float* x        = (const float*)d_in[0];
  const float* ln_in_w  = (const float*)d_in[1];
  const float* ln_in_b  = (const float*)d_in[2];
  const float* W_uvqk   = (const float*)d_in[3];
  const float* b_uvqk   = (const float*)d_in[4];
  const float* ln_out_w = (const float*)d_in[5];
  const float* ln_out_b = (const float*)d_in[6];
  const float* W_proj   = (const float*)d_in[7];
  float* out = (float*)d_out;
  char* ws = (char*)d_ws;

  unsigned short* Wq  = (unsigned short*)(ws);               // 8,388,608 B
  unsigned short* WpT = (unsigned short*)(ws + 8388608);     // 2,097,152 B
  unsigned short* nrm = (unsigned short*)(ws + 10485760);    // 33,554,432 B (normed, then attn out)
  unsigned short* mix = (unsigned short*)(ws + 44040192);    // 134,217,728 B
  unsigned short* vT  = (unsigned short*)(ws + 178257920);   // 33,554,432 B

  // 1. weights -> bf16
  cvt_bf16_kernel<<<2048, 256, 0, stream>>>(W_uvqk, Wq, 4194304 / 4);
  transpose_wp_kernel<<<dim3(16, 16), 256, 0, stream>>>(W_proj, WpT);
  // 2. LN1
  ln1_kernel<<<16384, 256, 0, stream>>>(x, ln_in_w, ln_in_b, nrm);
  // 3. GEMM1: mixed = silu(normed @ Wq^T + b)
  gemm_bt_kernel<0><<<dim3(128, 32), 256, 0, stream>>>(nrm, 1024, Wq, 1024, mix,
                                                       (float*)nullptr, 4096, b_uvqk, 1024);
  // 4. V transpose
  vtrans_kernel<<<dim3(16, 8, 16), 256, 0, stream>>>(mix, vT);
  // 5. attention -> nrm (reused as attn buffer)
  attn_kernel<<<dim3(16, 8, 16), 256, 0, stream>>>(mix, vT, nrm);
  // 6. LN2 * u -> parallel (mixed cols 1024..2047)
  ln2_kernel<<<16384, 256, 0, stream>>>(nrm, mix, ln_out_w, ln_out_b);
  // 7. GEMM2: out = parallel @ WpT^T + x
  gemm_bt_kernel<1><<<dim3(128, 8), 256, 0, stream>>>(mix + 1024, 4096, WpT, 1024,
                                                      (unsigned short*)nullptr, out, 1024, x, 1024);
}